// Round 9
// baseline (105.491 us; speedup 1.0000x reference)
//
#include <hip/hip_runtime.h>
#include <cstdint>
#include <cstddef>

typedef unsigned short u16;
typedef unsigned char u8;
typedef __bf16 bf16x8 __attribute__((ext_vector_type(8)));
typedef float f32x4 __attribute__((ext_vector_type(4)));
typedef float f32x2 __attribute__((ext_vector_type(2)));
typedef u16 u16x8 __attribute__((ext_vector_type(8)));

#define B_ 16384
#define D_ 64
#define MAXC_ 8
#define NCON_ 2000
#define NCONP_ 2048
#define TDIM_ 1024
#define HID_ 256

#define VMW(n) asm volatile("s_waitcnt vmcnt(" #n ")" ::: "memory")
#define BAR() __builtin_amdgcn_s_barrier()

__device__ inline u16 f2b(float f){
  unsigned u = __float_as_uint(f);
  u += 0x7fffu + ((u >> 16) & 1u);
  return (u16)(u >> 16);
}
__device__ inline float b2f(u16 u){ return __uint_as_float(((unsigned)u) << 16); }

__device__ inline unsigned pk2fp8(float a, float b){
  return (unsigned)__builtin_amdgcn_cvt_pk_fp8_f32(a, b, 0, false);
}
template<bool HI>
__device__ inline f32x2 unpk_fp8(unsigned v){
  return __builtin_amdgcn_cvt_pk_f32_fp8(v, HI);
}

__device__ inline void gload16(const void* g, void* l){
  __builtin_amdgcn_global_load_lds((const __attribute__((address_space(1))) unsigned*)g,
                                   (__attribute__((address_space(3))) unsigned*)l, 16, 0, 0);
}

__device__ inline float sigf(float x){ return 1.f / (1.f + __expf(-x)); }

// =================== k_prepw: weight transposes only ========================
__global__ __launch_bounds__(256) void k_prepw(
    const float* __restrict__ W1, const float* __restrict__ W2,
    const float* __restrict__ Wx, const float* __restrict__ Wh,
    const float* __restrict__ bx, const float* __restrict__ bh,
    u16* __restrict__ W1T, u16* __restrict__ W2T, u16* __restrict__ WxhT,
    float* __restrict__ bxh)
{
  int gid = blockIdx.x * 256 + threadIdx.x;
  if (gid < 262144){                       // W1T: n*1024 + k
    int n = gid >> 10, k = gid & 1023;
    W1T[gid] = f2b(W1[(size_t)k * 256 + n]);
  } else if (gid < 278528){                // W2T: n*256 + k
    int t = gid - 262144;
    int n = t >> 8, k = t & 255;
    W2T[t] = f2b(W2[(size_t)k * 64 + n]);
  } else if (gid < 360448){                // WxhT: c*320 + k, gate-interleaved
    int t = gid - 278528;
    int c = t / 320, k = t % 320;
    int g = (c >> 4) & 3;
    int d = (c >> 6) * 16 + (c & 15);
    float v = 0.f;
    if (k < 256){
      if (g == 0)      v = Wx[(size_t)k * 192 + d];
      else if (g == 1) v = Wx[(size_t)k * 192 + 64 + d];
      else if (g == 2) v = Wx[(size_t)k * 192 + 128 + d];
    } else {
      int kh = k - 256;
      if (g == 0)      v = Wh[(size_t)kh * 192 + d];
      else if (g == 1) v = Wh[(size_t)kh * 192 + 64 + d];
      else if (g == 3) v = Wh[(size_t)kh * 192 + 128 + d];
    }
    WxhT[t] = f2b(v);
  } else if (gid < 360704){                // bxh
    int c = gid - 360448;
    int g = (c >> 4) & 3;
    int d = (c >> 6) * 16 + (c & 15);
    float v;
    if (g == 0)      v = bx[d] + bh[d];
    else if (g == 1) v = bx[64 + d] + bh[64 + d];
    else if (g == 2) v = bx[128 + d];
    else             v = bh[128 + d];
    bxh[c] = v;
  }
}

// =================== k_core<QSIDE> ==========================================
// 16 rows/block, 512 thr / 8 waves. Qs[16][1024] bf16 resident (32 KB,
// kt-tile XOR swizzle); Bs region 32 KB staged per phase.
// QSIDE: gather from ex via pid; phases 1..6 (mix+GRU), outputs prob+h_next.
// !QSIDE: rows from con; writes cb8+cn+redc; exits after L2.
template<bool QSIDE>
__global__ __launch_bounds__(512) void k_core(
    const float* __restrict__ src_mat, const int* __restrict__ pid,
    u8* __restrict__ cb8w, float* __restrict__ cnw, float* __restrict__ redcw,
    const u8* __restrict__ cb8, const float* __restrict__ cn,
    const float* __restrict__ redc,
    const int* __restrict__ rci, const int* __restrict__ filt,
    const float* __restrict__ h, const float* __restrict__ emb,
    const float* __restrict__ op, const float* __restrict__ Wp,
    const float* __restrict__ bp,
    const u16* __restrict__ WxhT, const float* __restrict__ bxh,
    const u16* __restrict__ W1T, const float* __restrict__ b1,
    const u16* __restrict__ W2T, const float* __restrict__ b2,
    float* __restrict__ prob_out, float* __restrict__ outh)
{
  __shared__ char SM[65536];
  u16*   Qs = (u16*)SM;                       // [16] rows, stride 2048 B
  u16*   Bs = (u16*)(SM + 32768);             // [256][64] staging
  u16*   Hs = (u16*)(SM + 32768);             // [16][256] (alias, post-L1)
  float* Rq = (float*)(SM + 32768 + 8192);    // [16][64] f32 (post-L2)
  const int tid = threadIdx.x;
  const int lane = tid & 63;
  const int w = tid >> 6;
  const int lr = lane & 15, lq = lane >> 4;
  const int m0 = blockIdx.x << 4;

  // ---------- phase 1: load 16 rows f32 -> bf16 -> Qs (+cb8/cn for c) ------
  {
    const int row = tid >> 5, sub = tid & 31;
    const int gr = m0 + row;
    bool live = true;
    const float* src;
    if constexpr (QSIDE){
      src = src_mat + (size_t)pid[gr] * TDIM_ + sub * 32;
    } else {
      live = gr < NCON_;
      src = src_mat + (size_t)gr * TDIM_ + sub * 32;
    }
    float ss = 0.f;
    #pragma unroll
    for (int c = 0; c < 4; ++c){
      int cc = (c + sub) & 3;
      float4 a = {0,0,0,0}, b4 = {0,0,0,0};
      if (live){
        a  = *(const float4*)(src + cc * 8);
        b4 = *(const float4*)(src + cc * 8 + 4);
      }
      ss += a.x*a.x + a.y*a.y + a.z*a.z + a.w*a.w
          + b4.x*b4.x + b4.y*b4.y + b4.z*b4.z + b4.w*b4.w;
      u16x8 o = { f2b(a.x), f2b(a.y), f2b(a.z), f2b(a.w),
                  f2b(b4.x), f2b(b4.y), f2b(b4.z), f2b(b4.w) };
      int T = sub >> 1;
      int inner = ((sub & 1) * 64 + cc * 16) ^ ((row & 7) << 4);
      *(u16x8*)((char*)Qs + row * 2048 + T * 128 + inner) = o;
      if constexpr (!QSIDE){
        if (live){
          unsigned w0 = (pk2fp8(a.x * 32.f, a.y * 32.f) & 0xffffu)
                      | (pk2fp8(a.z * 32.f, a.w * 32.f) << 16);
          unsigned w1 = (pk2fp8(b4.x * 32.f, b4.y * 32.f) & 0xffffu)
                      | (pk2fp8(b4.z * 32.f, b4.w * 32.f) << 16);
          uint2 pk = { w0, w1 };
          *(uint2*)(cb8w + (size_t)gr * TDIM_ + sub * 32 + cc * 8) = pk;
        }
      }
    }
    if constexpr (!QSIDE){
      ss += __shfl_xor(ss, 1);  ss += __shfl_xor(ss, 2);
      ss += __shfl_xor(ss, 4);  ss += __shfl_xor(ss, 8);
      ss += __shfl_xor(ss, 16);
      if (live && sub == 0) cnw[gr] = sqrtf(ss);
    }
  }
  __syncthreads();

  // ---------- phase 2: L1 GEMM [16,1024]@W1T^T -> acc (cols w*32..+31) -----
  f32x4 acc[2] = {};
  for (int kt = 0; kt < 16; ++kt){
    #pragma unroll
    for (int i = 0; i < 4; ++i){
      int c2 = i * 512 + tid;
      int r2 = c2 >> 3, s2 = c2 & 7;
      gload16(W1T + (size_t)r2 * 1024 + kt * 64 + ((s2 ^ (r2 & 7)) << 3), &Bs[c2 * 8]);
    }
    VMW(0);
    BAR();
    #pragma unroll
    for (int ks = 0; ks < 2; ++ks){
      const int kb = ks * 64 + lq * 16;
      bf16x8 af = *(const bf16x8*)((const char*)Qs + lr * 2048 + kt * 128 +
                                   (kb ^ ((lr & 7) << 4)));
      #pragma unroll
      for (int fc = 0; fc < 2; ++fc){
        int rb = w * 32 + fc * 16 + lr;
        bf16x8 bf = *(const bf16x8*)((const char*)Bs + rb * 128 + (kb ^ ((rb & 7) << 4)));
        acc[fc] = __builtin_amdgcn_mfma_f32_16x16x32_bf16(af, bf, acc[fc], 0, 0, 0);
      }
    }
    BAR();
  }
  // hidden -> Hs (bias+relu+bf16), swizzled; Hs aliases Bs (all reads done)
  #pragma unroll
  for (int fc = 0; fc < 2; ++fc){
    int col = w * 32 + fc * 16 + lr;
    float bv = b1[col];
    #pragma unroll
    for (int j = 0; j < 4; ++j){
      int rr = lq * 4 + j;
      float v = fmaxf(acc[fc][j] + bv, 0.f);
      *(u16*)((char*)Hs + rr * 512 + ((col * 2) ^ ((rr & 7) << 4))) = f2b(v);
    }
  }
  __syncthreads();

  // ---------- phase 3: L2 [16,256]@W2T^T -> Rq (q) / redc (c) --------------
  if (w < 4){
    f32x4 acc2 = {};
    #pragma unroll
    for (int ks2 = 0; ks2 < 8; ++ks2){
      int kb2 = ks2 * 64 + lq * 16;
      bf16x8 af2 = *(const bf16x8*)((const char*)Hs + lr * 512 + (kb2 ^ ((lr & 7) << 4)));
      bf16x8 w2 = *(const bf16x8*)(W2T + (size_t)(w * 16 + lr) * 256 + ks2 * 32 + lq * 8);
      acc2 = __builtin_amdgcn_mfma_f32_16x16x32_bf16(af2, w2, acc2, 0, 0, 0);
    }
    int col = w * 16 + lr;
    float bv = b2[col];
    #pragma unroll
    for (int j = 0; j < 4; ++j){
      int rr = lq * 4 + j;
      if constexpr (QSIDE) Rq[rr * 64 + col] = acc2[j] + bv;
      else redcw[(size_t)(m0 + rr) * 64 + col] = acc2[j] + bv;
    }
  }
  if constexpr (!QSIDE) return;
  __syncthreads();

  // ---------- phase 4: mix (cosine/softmax/predictor), 2 rows per wave -----
  for (int i = 0; i < 2; ++i){
    const int r = w * 2 + i;
    const int b = m0 + r;
    // q cols: lane covers [lane*8, lane*8+8) and +512
    const int tb = (lane >> 3) * 128 + (((lane & 7) * 16) ^ ((r & 7) << 4));
    u16x8 qa = *(const u16x8*)((const char*)Qs + r * 2048 + tb);
    u16x8 qc = *(const u16x8*)((const char*)Qs + r * 2048 + 1024 + tb);
    float qf[16]; float ssq = 0.f;
    #pragma unroll
    for (int k = 0; k < 8; ++k){
      qf[k] = b2f(qa[k]); qf[8 + k] = b2f(qc[k]);
      ssq += qf[k] * qf[k] + qf[8 + k] * qf[8 + k];
    }
    int idxm[MAXC_];
    #pragma unroll
    for (int m = 0; m < MAXC_; ++m) idxm[m] = rci[b * MAXC_ + m];
    float dots[MAXC_];
    #pragma unroll
    for (int m = 0; m < MAXC_; ++m){
      const u8* crow = cb8 + (size_t)idxm[m] * TDIM_ + lane * 8;
      uint2 c1 = *(const uint2*)crow;
      uint2 c2 = *(const uint2*)(crow + 512);
      float s = 0.f; f32x2 p;
      p = unpk_fp8<false>(c1.x); s += qf[0]*p[0]  + qf[1]*p[1];
      p = unpk_fp8<true >(c1.x); s += qf[2]*p[0]  + qf[3]*p[1];
      p = unpk_fp8<false>(c1.y); s += qf[4]*p[0]  + qf[5]*p[1];
      p = unpk_fp8<true >(c1.y); s += qf[6]*p[0]  + qf[7]*p[1];
      p = unpk_fp8<false>(c2.x); s += qf[8]*p[0]  + qf[9]*p[1];
      p = unpk_fp8<true >(c2.x); s += qf[10]*p[0] + qf[11]*p[1];
      p = unpk_fp8<false>(c2.y); s += qf[12]*p[0] + qf[13]*p[1];
      p = unpk_fp8<true >(c2.y); s += qf[14]*p[0] + qf[15]*p[1];
      dots[m] = s;
    }
    #pragma unroll
    for (int o = 32; o; o >>= 1){
      #pragma unroll
      for (int m = 0; m < MAXC_; ++m) dots[m] += __shfl_xor(dots[m], o);
      ssq += __shfl_xor(ssq, o);
    }
    const float qnb = sqrtf(ssq);
    float sv[MAXC_]; float mx = -3.0e38f;
    #pragma unroll
    for (int m = 0; m < MAXC_; ++m){
      float dnm = fmaxf(qnb * cn[idxm[m]], 1e-8f);
      float s = (filt[b * MAXC_ + m] == 0) ? -1e9f : dots[m] * (1.f / 32.f) / dnm;
      sv[m] = s; mx = fmaxf(mx, s);
    }
    float se = 0.f;
    #pragma unroll
    for (int m = 0; m < MAXC_; ++m){ sv[m] = __expf(sv[m] - mx); se += sv[m]; }
    const float inv = 1.f / se;
    float rep = 0.f;
    #pragma unroll
    for (int m = 0; m < MAXC_; ++m) rep += sv[m] * redc[(size_t)idxm[m] * D_ + lane];
    rep *= inv;
    const float v0 = Rq[r * 64 + lane];
    const float hv = h[(size_t)b * D_ + lane];
    const float e0 = emb[(size_t)b * 128 + lane];
    const float e1 = emb[(size_t)b * 128 + 64 + lane];
    float p = hv * Wp[lane] + v0 * Wp[64 + lane] + rep * Wp[128 + lane]
            + e0 * Wp[192 + lane] + e1 * Wp[256 + lane];
    #pragma unroll
    for (int o = 32; o; o >>= 1) p += __shfl_xor(p, o);
    if (lane == 0) prob_out[b] = p + bp[0];
    const float o = op[b], om = 1.f - o;
    // xh row -> head of Qs[r] (row r's q-reads are complete for this wave)
    auto xst = [&](int col, float v){
      *(u16*)((char*)Qs + r * 2048 + ((col * 2) ^ ((r & 7) << 4))) = f2b(v);
    };
    xst(lane,        v0 * o  + e0 * om);
    xst(64 + lane,   rep * o + e1 * om);
    xst(128 + lane,  v0 * om + e0 * o);
    xst(192 + lane,  rep * om + e1 * o);
    xst(256 + lane,  hv);
  }
  __syncthreads();

  // ---------- phase 5: GRU GEMM [16,320]@WxhT^T + gates --------------------
  auto stageB = [&](int kt){
    #pragma unroll
    for (int i = 0; i < 4; ++i){
      int c2 = i * 512 + tid;
      int r2 = c2 >> 3, s2 = c2 & 7;
      gload16(WxhT + (size_t)r2 * 320 + kt * 64 + ((s2 ^ (r2 & 7)) << 3), &Bs[c2 * 8]);
    }
  };
  stageB(0);
  f32x4 accg[4] = {};
  for (int kt = 0; kt < 5; ++kt){
    VMW(0);
    BAR();
    if (w < 4){
      #pragma unroll
      for (int ks = 0; ks < 2; ++ks){
        const int kb = ks * 64 + lq * 16;
        bf16x8 af = *(const bf16x8*)((const char*)Qs + lr * 2048 +
                                     ((kt * 128 + kb) ^ ((lr & 7) << 4)));
        #pragma unroll
        for (int fc = 0; fc < 4; ++fc){
          int rb = w * 64 + fc * 16 + lr;
          bf16x8 bf = *(const bf16x8*)((const char*)Bs + rb * 128 + (kb ^ ((rb & 7) << 4)));
          accg[fc] = __builtin_amdgcn_mfma_f32_16x16x32_bf16(af, bf, accg[fc], 0, 0, 0);
        }
      }
    }
    BAR();
    if (kt < 4) stageB(kt + 1);
  }
  if (w < 4){
    const int d = w * 16 + lr;
    float bg[4];
    #pragma unroll
    for (int g = 0; g < 4; ++g) bg[g] = bxh[w * 64 + g * 16 + lr];
    #pragma unroll
    for (int j = 0; j < 4; ++j){
      float rv = sigf(accg[0][j] + bg[0]);
      float zv = sigf(accg[1][j] + bg[1]);
      float nv = tanhf(accg[2][j] + bg[2] + rv * (accg[3][j] + bg[3]));
      int rr = m0 + lq * 4 + j;
      float hv = h[(size_t)rr * 64 + d];
      outh[(size_t)rr * 64 + d] = (1.f - zv) * nv + zv * hv;
    }
  }
}

extern "C" void kernel_launch(void* const* d_in, const int* in_sizes, int n_in,
                              void* d_out, int out_size, void* d_ws, size_t ws_size,
                              hipStream_t stream) {
  const int*   prob_ids = (const int*)  d_in[0];
  const int*   rci      = (const int*)  d_in[1];
  const int*   filt     = (const int*)  d_in[2];
  const float* h        = (const float*)d_in[3];
  const float* emb      = (const float*)d_in[4];
  const float* op       = (const float*)d_in[5];
  const float* ex       = (const float*)d_in[6];
  const float* con      = (const float*)d_in[7];
  const float* W1       = (const float*)d_in[8];
  const float* b1       = (const float*)d_in[9];
  const float* W2       = (const float*)d_in[10];
  const float* b2       = (const float*)d_in[11];
  const float* Wp       = (const float*)d_in[12];
  const float* bp       = (const float*)d_in[13];
  const float* Wx       = (const float*)d_in[14];
  const float* Wh       = (const float*)d_in[15];
  const float* bx       = (const float*)d_in[16];
  const float* bh       = (const float*)d_in[17];
  float* out = (float*)d_out;

  char* w = (char*)d_ws;
  size_t off = 0;
  auto alloc = [&](size_t bytes){ size_t o = off; off = (off + bytes + 255) & ~(size_t)255; return o; };
  u8*    cb8  = (u8*)   (w + alloc((size_t)NCONP_ * TDIM_));      // 2 MB
  float* cn   = (float*)(w + alloc((size_t)NCONP_ * 4));
  float* redc = (float*)(w + alloc((size_t)NCONP_ * D_ * 4));     // 512 KB
  u16*   W1T  = (u16*)  (w + alloc((size_t)HID_ * TDIM_ * 2));
  u16*   W2T  = (u16*)  (w + alloc((size_t)D_ * HID_ * 2));
  u16*   WxhT = (u16*)  (w + alloc((size_t)256 * 320 * 2));
  float* bxh  = (float*)(w + alloc((size_t)256 * 4));

  k_prepw<<<1409, 256, 0, stream>>>(W1, W2, Wx, Wh, bx, bh, W1T, W2T, WxhT, bxh);

  k_core<false><<<NCONP_ / 16, 512, 0, stream>>>(
      con, nullptr, cb8, cn, redc,
      nullptr, nullptr, nullptr, nullptr, nullptr,
      nullptr, nullptr, nullptr, nullptr, nullptr,
      nullptr, nullptr,
      W1T, b1, W2T, b2, nullptr, nullptr);

  k_core<true><<<B_ / 16, 512, 0, stream>>>(
      ex, prob_ids, nullptr, nullptr, nullptr,
      cb8, cn, redc, rci, filt,
      h, emb, op, Wp, bp,
      WxhT, bxh,
      W1T, b1, W2T, b2, out, out + B_);
}